// Round 9
// baseline (145.041 us; speedup 1.0000x reference)
//
#include <hip/hip_runtime.h>
#include <hip/hip_bf16.h>
#include <math.h>

// Shapes (fixed by the reference problem)
#define BB 2
#define TT 2048
#define CC 512
#define HH 8
#define DD 64
#define KK 4
#define C3 1536
#define MROWS (BB*TT)          // 4096

// GEMM1 tiling: 128(m) x 64(n), BK=64, 256 threads (4 waves of 64x32)
#define G1_NT (C3/64)          // 24
#define G1_BLOCKS (G1_NT*(MROWS/128))  // 768
// GEMM2 tiling: 64x64, BK=64, 256 threads (4 waves of 32x32)
#define G2_NT (CC/64)          // 8
#define G2_BLOCKS (G2_NT*(MROWS/64))   // 512

typedef __attribute__((ext_vector_type(8))) short bf16x8;
typedef __attribute__((ext_vector_type(4))) float floatx4;

static __device__ __forceinline__ unsigned short f2bf(float f) {
  unsigned int u = __float_as_uint(f);
  return (unsigned short)((u + 0x7fffu + ((u >> 16) & 1u)) >> 16);
}
static __device__ __forceinline__ float bf2f(unsigned short u) {
  return __uint_as_float(((unsigned int)u) << 16);
}

// bijective XCD swizzle (block count divisible by 8)
static __device__ __forceinline__ int xcd_swz(int bid, int nblk) {
  const int cpx = nblk >> 3;
  return (bid & 7) * cpx + (bid >> 3);
}

// ---------------------------------------------------------------------------
// GEMM body: 128x64 tile, BK=64 (R7-verified). 16 MFMA/wave/barrier-pair.
// ---------------------------------------------------------------------------
template<bool BF16OUT>
static __device__ __forceinline__ void gemm_body(
    int bid, int nt,
    const unsigned short* __restrict__ A,
    const unsigned short* __restrict__ Bt,
    const float* __restrict__ bias,
    void* __restrict__ Cout, int N, int K) {
  __shared__ unsigned short As[128][64];   // 16 KB
  __shared__ unsigned short Bs[64][64];    // 8 KB
  const int tid  = threadIdx.x;
  const int wave = tid >> 6;
  const int lane = tid & 63;
  const int n0 = (bid % nt) * 64;
  const int m0 = (bid / nt) * 128;
  const int m_off = (wave >> 1) * 64;
  const int n_off = (wave & 1) * 32;
  const int fr = lane & 15;
  const int fq = lane >> 4;
  const int srow   = lane >> 3;
  const int schunk = ((lane & 7) ^ srow) * 8;

  floatx4 acc[4][2];
#pragma unroll
  for (int i = 0; i < 4; ++i)
#pragma unroll
    for (int j = 0; j < 2; ++j) acc[i][j] = (floatx4){0.f, 0.f, 0.f, 0.f};

  for (int k0 = 0; k0 < K; k0 += 64) {
#pragma unroll
    for (int s = 0; s < 4; ++s) {
      const int r0 = wave * 32 + s * 8;
      const unsigned short* ga = A + (size_t)(m0 + r0 + srow) * K + k0 + schunk;
      __builtin_amdgcn_global_load_lds(
          (const __attribute__((address_space(1))) void*)ga,
          (__attribute__((address_space(3))) void*)&As[r0][0], 16, 0, 0);
    }
#pragma unroll
    for (int s = 0; s < 2; ++s) {
      const int r0 = wave * 16 + s * 8;
      const unsigned short* gb = Bt + (size_t)(n0 + r0 + srow) * K + k0 + schunk;
      __builtin_amdgcn_global_load_lds(
          (const __attribute__((address_space(1))) void*)gb,
          (__attribute__((address_space(3))) void*)&Bs[r0][0], 16, 0, 0);
    }
    __syncthreads();
#pragma unroll
    for (int kk = 0; kk < 2; ++kk) {
      bf16x8 a[4], b[2];
#pragma unroll
      for (int i = 0; i < 4; ++i) {
        const int row = m_off + i * 16 + fr;
        a[i] = *(const bf16x8*)&As[row][(((kk << 2) + fq) ^ (row & 7)) * 8];
      }
#pragma unroll
      for (int j = 0; j < 2; ++j) {
        const int row = n_off + j * 16 + fr;
        b[j] = *(const bf16x8*)&Bs[row][(((kk << 2) + fq) ^ (row & 7)) * 8];
      }
#pragma unroll
      for (int i = 0; i < 4; ++i)
#pragma unroll
        for (int j = 0; j < 2; ++j)
          acc[i][j] = __builtin_amdgcn_mfma_f32_16x16x32_bf16(a[i], b[j], acc[i][j], 0, 0, 0);
    }
    __syncthreads();
  }
#pragma unroll
  for (int j = 0; j < 2; ++j) {
    int col = n0 + n_off + j * 16 + fr;
    float bv = bias[col];
#pragma unroll
    for (int i = 0; i < 4; ++i) {
#pragma unroll
      for (int r = 0; r < 4; ++r) {
        int row = m0 + m_off + i * 16 + fq * 4 + r;
        float v = acc[i][j][r] + bv;
        if (BF16OUT) ((unsigned short*)Cout)[(size_t)row * N + col] = f2bf(v);
        else         ((float*)Cout)[(size_t)row * N + col] = v;
      }
    }
  }
}

// ---------------------------------------------------------------------------
// GEMM body, 64x64 tile, BK=64 (R7-verified)
// ---------------------------------------------------------------------------
static __device__ __forceinline__ void gemm_body64(
    int bid, int nt,
    const unsigned short* __restrict__ A,
    const unsigned short* __restrict__ Bt,
    const float* __restrict__ bias,
    float* __restrict__ Cout, int N, int K) {
  __shared__ unsigned short As[64][64];   // 8 KB
  __shared__ unsigned short Bs[64][64];   // 8 KB
  const int tid  = threadIdx.x;
  const int wave = tid >> 6;
  const int lane = tid & 63;
  const int n0 = (bid % nt) * 64;
  const int m0 = (bid / nt) * 64;
  const int m_off = (wave >> 1) * 32;
  const int n_off = (wave & 1) * 32;
  const int fr = lane & 15;
  const int fq = lane >> 4;
  const int srow   = lane >> 3;
  const int schunk = ((lane & 7) ^ srow) * 8;

  floatx4 acc[2][2];
#pragma unroll
  for (int i = 0; i < 2; ++i)
#pragma unroll
    for (int j = 0; j < 2; ++j) acc[i][j] = (floatx4){0.f, 0.f, 0.f, 0.f};

  for (int k0 = 0; k0 < K; k0 += 64) {
#pragma unroll
    for (int s = 0; s < 2; ++s) {
      const int r0 = wave * 16 + s * 8;
      const unsigned short* ga = A + (size_t)(m0 + r0 + srow) * K + k0 + schunk;
      __builtin_amdgcn_global_load_lds(
          (const __attribute__((address_space(1))) void*)ga,
          (__attribute__((address_space(3))) void*)&As[r0][0], 16, 0, 0);
      const unsigned short* gb = Bt + (size_t)(n0 + r0 + srow) * K + k0 + schunk;
      __builtin_amdgcn_global_load_lds(
          (const __attribute__((address_space(1))) void*)gb,
          (__attribute__((address_space(3))) void*)&Bs[r0][0], 16, 0, 0);
    }
    __syncthreads();
#pragma unroll
    for (int kk = 0; kk < 2; ++kk) {
      bf16x8 a[2], b[2];
#pragma unroll
      for (int i = 0; i < 2; ++i) {
        const int row = m_off + i * 16 + fr;
        a[i] = *(const bf16x8*)&As[row][(((kk << 2) + fq) ^ (row & 7)) * 8];
      }
#pragma unroll
      for (int j = 0; j < 2; ++j) {
        const int row = n_off + j * 16 + fr;
        b[j] = *(const bf16x8*)&Bs[row][(((kk << 2) + fq) ^ (row & 7)) * 8];
      }
#pragma unroll
      for (int i = 0; i < 2; ++i)
#pragma unroll
        for (int j = 0; j < 2; ++j)
          acc[i][j] = __builtin_amdgcn_mfma_f32_16x16x32_bf16(a[i], b[j], acc[i][j], 0, 0, 0);
    }
    __syncthreads();
  }
#pragma unroll
  for (int j = 0; j < 2; ++j) {
    int col = n0 + n_off + j * 16 + fr;
    float bv = bias[col];
#pragma unroll
    for (int i = 0; i < 2; ++i) {
#pragma unroll
      for (int r = 0; r < 4; ++r) {
        int row = m0 + m_off + i * 16 + fq * 4 + r;
        Cout[(size_t)row * N + col] = acc[i][j][r] + bv;
      }
    }
  }
}

// ---------------------------------------------------------------------------
// sorted top-4 helpers: total order (value desc, index asc) = jax.lax.top_k
// ---------------------------------------------------------------------------
static __device__ __forceinline__ bool kv_better(float av, int ai, float bv, int bi) {
  return av > bv || (av == bv && ai < bi);
}
static __device__ __forceinline__ void kv_ce(float* v, int* i, int a, int b) {
  if (!kv_better(v[a], i[a], v[b], i[b])) {
    float tv = v[a]; v[a] = v[b]; v[b] = tv;
    int   ti = i[a]; i[a] = i[b]; i[b] = ti;
  }
}
static __device__ __forceinline__ void kv_merge(
    float* av, int* ai, const float* bv, const int* bi) {
  float cv[4]; int ci[4];
#pragma unroll
  for (int j = 0; j < 4; ++j) {
    bool t = kv_better(av[j], ai[j], bv[3 - j], bi[3 - j]);
    cv[j] = t ? av[j] : bv[3 - j];
    ci[j] = t ? ai[j] : bi[3 - j];
  }
  kv_ce(cv, ci, 0, 2); kv_ce(cv, ci, 1, 3);
  kv_ce(cv, ci, 0, 1); kv_ce(cv, ci, 2, 3);
#pragma unroll
  for (int j = 0; j < 4; ++j) { av[j] = cv[j]; ai[j] = ci[j]; }
}

// ---------------------------------------------------------------------------
// top-4 body (R0-proven): per-thread sorted-4 of 8 elems, 6-step butterfly
// bitonic merge, one barrier for the cross-wave merge. 256 threads.
// Runs as filler blocks co-scheduled with GEMM1 (depends only on tau).
// ---------------------------------------------------------------------------
static __device__ __forceinline__ void topk_body(
    int row, const float* __restrict__ tau, int* __restrict__ idx_out) {
  const int tid = threadIdx.x;
  const float4* rp = (const float4*)(tau + (size_t)row * TT);
  float4 f0 = rp[tid * 2], f1 = rp[tid * 2 + 1];
  float e[8] = { f0.x, f0.y, f0.z, f0.w, f1.x, f1.y, f1.z, f1.w };
  const int base = tid * 8;

  float tv[4] = { -1e30f, -1e30f, -1e30f, -1e30f };
  int   ti[4] = { 1 << 30, 1 << 30, 1 << 30, 1 << 30 };
#pragma unroll
  for (int k = 0; k < 8; ++k) {
    float v = e[k];
    if (v > tv[3]) {                 // strict >: increasing idx keeps earlier
      tv[3] = v; ti[3] = base + k;
      if (tv[3] > tv[2]) { float a=tv[2]; tv[2]=tv[3]; tv[3]=a; int c=ti[2]; ti[2]=ti[3]; ti[3]=c; }
      if (tv[2] > tv[1]) { float a=tv[1]; tv[1]=tv[2]; tv[2]=a; int c=ti[1]; ti[1]=ti[2]; ti[2]=c; }
      if (tv[1] > tv[0]) { float a=tv[0]; tv[0]=tv[1]; tv[1]=a; int c=ti[0]; ti[0]=ti[1]; ti[1]=c; }
    }
  }
  // butterfly allreduce across the wave (6 steps)
#pragma unroll
  for (int step = 1; step <= 32; step <<= 1) {
    float bv[4]; int bi[4];
#pragma unroll
    for (int j = 0; j < 4; ++j) {
      bv[j] = __shfl_xor(tv[j], step, 64);
      bi[j] = __shfl_xor(ti[j], step, 64);
    }
    kv_merge(tv, ti, bv, bi);
  }
  // cross-wave merge via LDS (4 waves)
  __shared__ float swv[4][4];
  __shared__ int   swi[4][4];
  const int wave = tid >> 6, lane = tid & 63;
  if (lane == 0) {
#pragma unroll
    for (int j = 0; j < 4; ++j) { swv[wave][j] = tv[j]; swi[wave][j] = ti[j]; }
  }
  __syncthreads();
  if (tid == 0) {
    float m0[4], m1[4]; int x0[4], x1[4];
#pragma unroll
    for (int j = 0; j < 4; ++j) { m0[j] = swv[0][j]; x0[j] = swi[0][j]; }
#pragma unroll
    for (int j = 0; j < 4; ++j) { m1[j] = swv[1][j]; x1[j] = swi[1][j]; }
    kv_merge(m0, x0, m1, x1);
#pragma unroll
    for (int j = 0; j < 4; ++j) { m1[j] = swv[2][j]; x1[j] = swi[2][j]; }
    float m2[4]; int x2[4];
#pragma unroll
    for (int j = 0; j < 4; ++j) { m2[j] = swv[3][j]; x2[j] = swi[3][j]; }
    kv_merge(m1, x1, m2, x2);
    kv_merge(m0, x0, m1, x1);
    int4 w = { x0[0], x0[1], x0[2], x0[3] };
    *((int4*)(idx_out + row * KK)) = w;
  }
}

// ---------------------------------------------------------------------------
// transpose+convert body
// ---------------------------------------------------------------------------
static __device__ __forceinline__ void transpose_body(
    int t, int nbx, const float* __restrict__ W, unsigned short* __restrict__ Wt,
    int R, int Cn) {
  __shared__ unsigned short tile[32][33];
  const int c0 = (t % nbx) * 32, r0 = (t / nbx) * 32;
  const int tx = threadIdx.x & 31, ty = threadIdx.x >> 5;
#pragma unroll
  for (int i = 0; i < 4; ++i) {
    int r = ty + i * 8;
    tile[r][tx] = f2bf(W[(size_t)(r0 + r) * Cn + c0 + tx]);
  }
  __syncthreads();
#pragma unroll
  for (int i = 0; i < 4; ++i) {
    int r = ty + i * 8;
    Wt[(size_t)(c0 + r) * R + r0 + tx] = tile[tx][r];
  }
}

// ---------------------------------------------------------------------------
// Kernel 1: input conversions
// ---------------------------------------------------------------------------
__global__ __launch_bounds__(256) void prep_kernel(
    const float* __restrict__ x, unsigned short* __restrict__ x_bf,
    const float* __restrict__ Wqkv, unsigned short* __restrict__ wqkv_t,
    const float* __restrict__ Wproj, unsigned short* __restrict__ wproj_t) {
  const int bid = blockIdx.x;
  if (bid < 1024) {
    int g = bid * 256 + threadIdx.x;
    const float4* p = (const float4*)x;
    float4 f0 = p[g * 2], f1 = p[g * 2 + 1];
    union { unsigned short u[8]; uint4 v; } pk;
    pk.u[0]=f2bf(f0.x); pk.u[1]=f2bf(f0.y); pk.u[2]=f2bf(f0.z); pk.u[3]=f2bf(f0.w);
    pk.u[4]=f2bf(f1.x); pk.u[5]=f2bf(f1.y); pk.u[6]=f2bf(f1.z); pk.u[7]=f2bf(f1.w);
    ((uint4*)x_bf)[g] = pk.v;
  } else if (bid < 1024 + 768) {
    transpose_body(bid - 1024, C3 / 32, Wqkv, wqkv_t, CC, C3);
  } else {
    transpose_body(bid - 1792, CC / 32, Wproj, wproj_t, CC, CC);
  }
}

// ---------------------------------------------------------------------------
// Kernel 2: GEMM1 (qkv, bf16 out, XCD-swizzled, BK=64) blocks [0,768)
// + topk filler blocks [768, 768+4096). topk depends only on tau, so it
// rides free in CU slack / idle HBM BW during the GEMM (R0-proven).
// ---------------------------------------------------------------------------
__global__ __launch_bounds__(256) void gemm1_topk_kernel(
    const unsigned short* __restrict__ x_bf,
    const unsigned short* __restrict__ wqkv_t,
    const float* __restrict__ bqkv, unsigned short* __restrict__ qkv_bf,
    const float* __restrict__ tau, int* __restrict__ idx_out) {
  if (blockIdx.x < G1_BLOCKS)
    gemm_body<true>(xcd_swz(blockIdx.x, G1_BLOCKS), G1_NT,
                    x_bf, wqkv_t, bqkv, qkv_bf, C3, CC);
  else
    topk_body(blockIdx.x - G1_BLOCKS, tau, idx_out);
}

// ---------------------------------------------------------------------------
// Kernel 3: 2-ROW attn + tau EMA, topk REMOVED from the serial chain
// (idx precomputed in K2). Chain is now: idx load -> gather -> reduce ->
// softmax -> attn write; the tau-row load (EMA) and q loads issue at block
// start and hide under the gathers. 2-row ILP throughout (R8-verified).
// All per-row arithmetic verbatim from the R8-passing kernel.
// 2048 blocks x 256 threads.
// ---------------------------------------------------------------------------
__global__ __launch_bounds__(256) void row2_kernel(
    const unsigned short* __restrict__ qkv, const float* __restrict__ tau,
    const int* __restrict__ idx_in, unsigned short* __restrict__ attn_bf,
    float* __restrict__ tau_out) {
  const int rowA = blockIdx.x * 2;
  const int rowB = rowA + 1;
  const int bA   = rowA >> 11;
  const int bB   = rowB >> 11;
  const int tid  = threadIdx.x;
  const int wv   = tid >> 6;
  const int lane = tid & 63;

  __shared__ int   idx4[2][KK];
  __shared__ float tau4[2][KK];
  __shared__ float ps[2][HH][KK];
  __shared__ float s3s[2][KK];
  __shared__ float wsum[2][4];

  // ---- stage idx + tau4 (two rows on two waves); issue tau-row + q loads ----
  if (tid < KK) {
    int s = idx_in[rowA * KK + tid];
    idx4[0][tid] = s;
    tau4[0][tid] = tau[(size_t)rowA * TT + s];
  } else if (tid >= 64 && tid < 64 + KK) {
    const int j = tid - 64;
    int s = idx_in[rowB * KK + j];
    idx4[1][j] = s;
    tau4[1][j] = tau[(size_t)rowB * TT + s];
  }
  const float4* rpA = (const float4*)(tau + (size_t)rowA * TT);
  const float4* rpB = (const float4*)(tau + (size_t)rowB * TT);
  float4 a0 = rpA[tid * 2], a1 = rpA[tid * 2 + 1];
  float4 b0 = rpB[tid * 2], b1 = rpB[tid * 2 + 1];
  float qvA[2], qvB[2];
  qvA[0] = bf2f(qkv[(size_t)rowA * C3 + wv * DD + lane]);
  qvA[1] = bf2f(qkv[(size_t)rowA * C3 + (wv + 4) * DD + lane]);
  qvB[0] = bf2f(qkv[(size_t)rowB * C3 + wv * DD + lane]);
  qvB[1] = bf2f(qkv[(size_t)rowB * C3 + (wv + 4) * DD + lane]);
  float eA[8] = { a0.x, a0.y, a0.z, a0.w, a1.x, a1.y, a1.z, a1.w };
  float eB[8] = { b0.x, b0.y, b0.z, b0.w, b1.x, b1.y, b1.z, b1.w };
  const int base = tid * 8;
  __syncthreads();

  int   i4A[KK], i4B[KK]; float t4A[KK], t4B[KK];
#pragma unroll
  for (int j = 0; j < KK; ++j) {
    i4A[j] = idx4[0][j]; t4A[j] = tau4[0][j];
    i4B[j] = idx4[1][j]; t4B[j] = tau4[1][j];
  }

  // ---- sparse attention: wave wv = heads wv, wv+4; rows interleaved ----
#pragma unroll
  for (int hh = 0; hh < 2; ++hh) {
    const int h = wv + hh * 4;
    float kvA[KK], vvA[KK], kvB[KK], vvB[KK];
#pragma unroll
    for (int j = 0; j < KK; ++j) {        // 16 loads in flight
      size_t bsA = ((size_t)(bA * TT + i4A[j])) * C3 + h * DD + lane;
      size_t bsB = ((size_t)(bB * TT + i4B[j])) * C3 + h * DD + lane;
      kvA[j] = bf2f(qkv[bsA + CC]);
      vvA[j] = bf2f(qkv[bsA + 2 * CC]);
      kvB[j] = bf2f(qkv[bsB + CC]);
      vvB[j] = bf2f(qkv[bsB + 2 * CC]);
    }
    float pA[KK], pB[KK];
#pragma unroll
    for (int j = 0; j < KK; ++j) { pA[j] = qvA[hh] * kvA[j]; pB[j] = qvB[hh] * kvB[j]; }
#pragma unroll
    for (int off = 32; off > 0; off >>= 1) {
#pragma unroll
      for (int j = 0; j < KK; ++j) pA[j] += __shfl_xor(pA[j], off, 64);
#pragma unroll
      for (int j = 0; j < KK; ++j) pB[j] += __shfl_xor(pB[j], off, 64);
    }
    float lgA[KK], lgB[KK];
#pragma unroll
    for (int j = 0; j < KK; ++j) {
      lgA[j] = pA[j] * 0.125f + 2.5f * logf(t4A[j] + 1e-8f);
      lgB[j] = pB[j] * 0.125f + 2.5f * logf(t4B[j] + 1e-8f);
    }
    float mA = fmaxf(fmaxf(lgA[0], lgA[1]), fmaxf(lgA[2], lgA[3]));
    float mB = fmaxf(fmaxf(lgB[0], lgB[1]), fmaxf(lgB[2], lgB[3]));
    float dA = 0.f, dB = 0.f;
#pragma unroll
    for (int j = 0; j < KK; ++j) { pA[j] = expf(lgA[j] - mA); dA += pA[j]; }
#pragma unroll
    for (int j = 0; j < KK; ++j) { pB[j] = expf(lgB[j] - mB); dB += pB[j]; }
    float ivA = 1.f / dA, ivB = 1.f / dB;
#pragma unroll
    for (int j = 0; j < KK; ++j) { pA[j] *= ivA; pB[j] *= ivB; }
    float oA = 0.f, oB = 0.f;
#pragma unroll
    for (int j = 0; j < KK; ++j) { oA += pA[j] * vvA[j]; oB += pB[j] * vvB[j]; }
    attn_bf[(size_t)rowA * CC + h * DD + lane] = f2bf(oA);
    attn_bf[(size_t)rowB * CC + h * DD + lane] = f2bf(oB);
    if (lane < KK) { ps[0][h][lane] = pA[lane]; ps[1][h][lane] = pB[lane]; }
  }
  __syncthreads();
  // signal^3 for the two rows on two different waves (parallel)
  if (tid < KK) {
    float s = 0.f;
#pragma unroll
    for (int k = 0; k < HH; ++k) s += ps[0][k][tid];
    s *= (1.0f / HH);
    s3s[0][tid] = s * s * s;
  } else if (tid >= 64 && tid < 64 + KK) {
    const int j = tid - 64;
    float s = 0.f;
#pragma unroll
    for (int k = 0; k < HH; ++k) s += ps[1][k][j];
    s *= (1.0f / HH);
    s3s[1][j] = s * s * s;
  }
  __syncthreads();

  // ---- tau EMA + normalize + clip, both rows interleaved ----
  float s3A[KK], s3B[KK];
#pragma unroll
  for (int j = 0; j < KK; ++j) { s3A[j] = s3s[0][j]; s3B[j] = s3s[1][j]; }
  const float keep = 1.0f - 0.085f;
  float locA = 0.f, locB = 0.f;
#pragma unroll
  for (int i = 0; i < 8; ++i) {
    float ta = keep * eA[i];
    float tb = keep * eB[i];
#pragma unroll
    for (int j = 0; j < KK; ++j) {
      if (base + i == i4A[j]) ta += s3A[j];
      if (base + i == i4B[j]) tb += s3B[j];
    }
    eA[i] = ta; locA += ta;
    eB[i] = tb; locB += tb;
  }
#pragma unroll
  for (int off = 32; off > 0; off >>= 1) {
    locA += __shfl_xor(locA, off, 64);
    locB += __shfl_xor(locB, off, 64);
  }
  if (lane == 0) { wsum[0][wv] = locA; wsum[1][wv] = locB; }
  __syncthreads();
  // per-thread broadcast sum (same add order as tid==0 path -> bit-identical)
  float totA = wsum[0][0] + wsum[0][1] + wsum[0][2] + wsum[0][3];
  float totB = wsum[1][0] + wsum[1][1] + wsum[1][2] + wsum[1][3];
  float invA = 1.f / (totA + 1e-8f);
  float invB = 1.f / (totB + 1e-8f);
  float4* opA = (float4*)(tau_out + (size_t)rowA * TT);
  float4 oa0 = { fminf(eA[0]*invA,5.f), fminf(eA[1]*invA,5.f), fminf(eA[2]*invA,5.f), fminf(eA[3]*invA,5.f) };
  float4 oa1 = { fminf(eA[4]*invA,5.f), fminf(eA[5]*invA,5.f), fminf(eA[6]*invA,5.f), fminf(eA[7]*invA,5.f) };
  opA[tid * 2] = oa0;
  opA[tid * 2 + 1] = oa1;
  float4* opB = (float4*)(tau_out + (size_t)rowB * TT);
  float4 ob0 = { fminf(eB[0]*invB,5.f), fminf(eB[1]*invB,5.f), fminf(eB[2]*invB,5.f), fminf(eB[3]*invB,5.f) };
  float4 ob1 = { fminf(eB[4]*invB,5.f), fminf(eB[5]*invB,5.f), fminf(eB[6]*invB,5.f), fminf(eB[7]*invB,5.f) };
  opB[tid * 2] = ob0;
  opB[tid * 2 + 1] = ob1;
}

// ---------------------------------------------------------------------------
// Kernel 4: GEMM2 (out, fp32), 64x64 tiles, BK=64, XCD-swizzled
// ---------------------------------------------------------------------------
__global__ __launch_bounds__(256) void gemm2_kernel(
    const unsigned short* __restrict__ attn_bf,
    const unsigned short* __restrict__ wproj_t,
    const float* __restrict__ bproj, float* __restrict__ out) {
  gemm_body64(xcd_swz(blockIdx.x, G2_BLOCKS), G2_NT,
              attn_bf, wproj_t, bproj, out, CC, CC);
}

// ---------------------------------------------------------------------------
extern "C" void kernel_launch(void* const* d_in, const int* in_sizes, int n_in,
                              void* d_out, int out_size, void* d_ws, size_t ws_size,
                              hipStream_t stream) {
  const float* x     = (const float*)d_in[0];   // [B,T,C]
  const float* tau   = (const float*)d_in[1];   // [B,T,T]
  const float* Wqkv  = (const float*)d_in[2];   // [C,3C]
  const float* bqkv  = (const float*)d_in[3];   // [3C]
  const float* Wproj = (const float*)d_in[4];   // [C,C]
  const float* bproj = (const float*)d_in[5];   // [C]

  float* out     = (float*)d_out;               // [B,T,C]
  float* tau_new = out + (size_t)MROWS * CC;    // [B,T,T]

  char* w = (char*)d_ws;
  unsigned short* qkv_bf  = (unsigned short*)w; w += (size_t)MROWS * C3 * 2;
  unsigned short* x_bf    = (unsigned short*)w; w += (size_t)MROWS * CC * 2;
  unsigned short* wqkv_t  = (unsigned short*)w; w += (size_t)C3 * CC * 2;
  unsigned short* wproj_t = (unsigned short*)w; w += (size_t)CC * CC * 2;
  unsigned short* attn_bf = (unsigned short*)w; w += (size_t)MROWS * CC * 2;
  int* idx = (int*)w;

  // 1) converts: x->bf16, Wqkv^T, Wproj^T
  prep_kernel<<<2048, 256, 0, stream>>>(x, x_bf, Wqkv, wqkv_t, Wproj, wproj_t);

  // 2) qkv GEMM + topk filler blocks (topk depends only on tau)
  gemm1_topk_kernel<<<G1_BLOCKS + MROWS, 256, 0, stream>>>(
      x_bf, wqkv_t, bqkv, qkv_bf, tau, idx);

  // 3) 2-row attn + tau EMA (topk removed from the serial chain)
  row2_kernel<<<MROWS / 2, 256, 0, stream>>>(qkv_bf, tau, idx, attn_bf, tau_new);

  // 4) out GEMM (fp32), 64x64 tiles, BK=64, XCD-swizzled
  gemm2_kernel<<<G2_BLOCKS, 256, 0, stream>>>(attn_bf, wproj_t, bproj, out);
}

// Round 10
// 138.574 us; speedup vs baseline: 1.0467x; 1.0467x over previous
//
#include <hip/hip_runtime.h>
#include <hip/hip_bf16.h>
#include <math.h>

// Shapes (fixed by the reference problem)
#define BB 2
#define TT 2048
#define CC 512
#define HH 8
#define DD 64
#define KK 4
#define C3 1536
#define MROWS (BB*TT)          // 4096

// GEMM1 tiling: 128(m) x 64(n), BK=64, 256 threads (4 waves of 64x32)
#define G1_NT (C3/64)          // 24
#define G1_BLOCKS (G1_NT*(MROWS/128))  // 768
// GEMM2 tiling: 64x64, BK=64, 256 threads (4 waves of 32x32)
#define G2_NT (CC/64)          // 8
#define G2_BLOCKS (G2_NT*(MROWS/64))   // 512

typedef __attribute__((ext_vector_type(8))) short bf16x8;
typedef __attribute__((ext_vector_type(4))) float floatx4;

static __device__ __forceinline__ unsigned short f2bf(float f) {
  unsigned int u = __float_as_uint(f);
  return (unsigned short)((u + 0x7fffu + ((u >> 16) & 1u)) >> 16);
}
static __device__ __forceinline__ float bf2f(unsigned short u) {
  return __uint_as_float(((unsigned int)u) << 16);
}

// bijective XCD swizzle (block count divisible by 8): XCD j gets a
// contiguous chunk of tiles -> A-panels stay resident in that XCD's L2.
static __device__ __forceinline__ int xcd_swz(int bid, int nblk) {
  const int cpx = nblk >> 3;
  return (bid & 7) * cpx + (bid >> 3);
}

// ---------------------------------------------------------------------------
// GEMM body: C = A[M,K] @ Bt[N,K]^T + bias. 128x64 tile, BK=64, 256 thr
// (4 waves, each 64m x 32n). Rows are 8 chunks of 16 B; chunk c of row r
// lives at position c ^ (r&7) (linear global_load_lds dest, pre-swizzled
// global source); reads apply the same XOR. 16 MFMA/wave/barrier-pair.
// ---------------------------------------------------------------------------
template<bool BF16OUT>
static __device__ __forceinline__ void gemm_body(
    int bid, int nt,
    const unsigned short* __restrict__ A,
    const unsigned short* __restrict__ Bt,
    const float* __restrict__ bias,
    void* __restrict__ Cout, int N, int K) {
  __shared__ unsigned short As[128][64];   // 16 KB
  __shared__ unsigned short Bs[64][64];    // 8 KB
  const int tid  = threadIdx.x;
  const int wave = tid >> 6;
  const int lane = tid & 63;
  const int n0 = (bid % nt) * 64;
  const int m0 = (bid / nt) * 128;
  const int m_off = (wave >> 1) * 64;
  const int n_off = (wave & 1) * 32;
  const int fr = lane & 15;
  const int fq = lane >> 4;
  const int srow   = lane >> 3;
  const int schunk = ((lane & 7) ^ srow) * 8;

  floatx4 acc[4][2];
#pragma unroll
  for (int i = 0; i < 4; ++i)
#pragma unroll
    for (int j = 0; j < 2; ++j) acc[i][j] = (floatx4){0.f, 0.f, 0.f, 0.f};

  for (int k0 = 0; k0 < K; k0 += 64) {
#pragma unroll
    for (int s = 0; s < 4; ++s) {
      const int r0 = wave * 32 + s * 8;
      const unsigned short* ga = A + (size_t)(m0 + r0 + srow) * K + k0 + schunk;
      __builtin_amdgcn_global_load_lds(
          (const __attribute__((address_space(1))) void*)ga,
          (__attribute__((address_space(3))) void*)&As[r0][0], 16, 0, 0);
    }
#pragma unroll
    for (int s = 0; s < 2; ++s) {
      const int r0 = wave * 16 + s * 8;
      const unsigned short* gb = Bt + (size_t)(n0 + r0 + srow) * K + k0 + schunk;
      __builtin_amdgcn_global_load_lds(
          (const __attribute__((address_space(1))) void*)gb,
          (__attribute__((address_space(3))) void*)&Bs[r0][0], 16, 0, 0);
    }
    __syncthreads();
#pragma unroll
    for (int kk = 0; kk < 2; ++kk) {
      bf16x8 a[4], b[2];
#pragma unroll
      for (int i = 0; i < 4; ++i) {
        const int row = m_off + i * 16 + fr;
        a[i] = *(const bf16x8*)&As[row][(((kk << 2) + fq) ^ (row & 7)) * 8];
      }
#pragma unroll
      for (int j = 0; j < 2; ++j) {
        const int row = n_off + j * 16 + fr;
        b[j] = *(const bf16x8*)&Bs[row][(((kk << 2) + fq) ^ (row & 7)) * 8];
      }
#pragma unroll
      for (int i = 0; i < 4; ++i)
#pragma unroll
        for (int j = 0; j < 2; ++j)
          acc[i][j] = __builtin_amdgcn_mfma_f32_16x16x32_bf16(a[i], b[j], acc[i][j], 0, 0, 0);
    }
    __syncthreads();
  }
#pragma unroll
  for (int j = 0; j < 2; ++j) {
    int col = n0 + n_off + j * 16 + fr;
    float bv = bias[col];
#pragma unroll
    for (int i = 0; i < 4; ++i) {
#pragma unroll
      for (int r = 0; r < 4; ++r) {
        int row = m0 + m_off + i * 16 + fq * 4 + r;
        float v = acc[i][j][r] + bv;
        if (BF16OUT) ((unsigned short*)Cout)[(size_t)row * N + col] = f2bf(v);
        else         ((float*)Cout)[(size_t)row * N + col] = v;
      }
    }
  }
}

// ---------------------------------------------------------------------------
// GEMM body, 64x64 tile, BK=64 (same verified swizzle math).
// 4 waves, each 32m x 32n (acc 2x2). 8 MFMA per wave per barrier pair.
// ---------------------------------------------------------------------------
static __device__ __forceinline__ void gemm_body64(
    int bid, int nt,
    const unsigned short* __restrict__ A,
    const unsigned short* __restrict__ Bt,
    const float* __restrict__ bias,
    float* __restrict__ Cout, int N, int K) {
  __shared__ unsigned short As[64][64];   // 8 KB
  __shared__ unsigned short Bs[64][64];   // 8 KB
  const int tid  = threadIdx.x;
  const int wave = tid >> 6;
  const int lane = tid & 63;
  const int n0 = (bid % nt) * 64;
  const int m0 = (bid / nt) * 64;
  const int m_off = (wave >> 1) * 32;
  const int n_off = (wave & 1) * 32;
  const int fr = lane & 15;
  const int fq = lane >> 4;
  const int srow   = lane >> 3;
  const int schunk = ((lane & 7) ^ srow) * 8;

  floatx4 acc[2][2];
#pragma unroll
  for (int i = 0; i < 2; ++i)
#pragma unroll
    for (int j = 0; j < 2; ++j) acc[i][j] = (floatx4){0.f, 0.f, 0.f, 0.f};

  for (int k0 = 0; k0 < K; k0 += 64) {
#pragma unroll
    for (int s = 0; s < 2; ++s) {
      const int r0 = wave * 16 + s * 8;
      const unsigned short* ga = A + (size_t)(m0 + r0 + srow) * K + k0 + schunk;
      __builtin_amdgcn_global_load_lds(
          (const __attribute__((address_space(1))) void*)ga,
          (__attribute__((address_space(3))) void*)&As[r0][0], 16, 0, 0);
      const unsigned short* gb = Bt + (size_t)(n0 + r0 + srow) * K + k0 + schunk;
      __builtin_amdgcn_global_load_lds(
          (const __attribute__((address_space(1))) void*)gb,
          (__attribute__((address_space(3))) void*)&Bs[r0][0], 16, 0, 0);
    }
    __syncthreads();
#pragma unroll
    for (int kk = 0; kk < 2; ++kk) {
      bf16x8 a[2], b[2];
#pragma unroll
      for (int i = 0; i < 2; ++i) {
        const int row = m_off + i * 16 + fr;
        a[i] = *(const bf16x8*)&As[row][(((kk << 2) + fq) ^ (row & 7)) * 8];
      }
#pragma unroll
      for (int j = 0; j < 2; ++j) {
        const int row = n_off + j * 16 + fr;
        b[j] = *(const bf16x8*)&Bs[row][(((kk << 2) + fq) ^ (row & 7)) * 8];
      }
#pragma unroll
      for (int i = 0; i < 2; ++i)
#pragma unroll
        for (int j = 0; j < 2; ++j)
          acc[i][j] = __builtin_amdgcn_mfma_f32_16x16x32_bf16(a[i], b[j], acc[i][j], 0, 0, 0);
    }
    __syncthreads();
  }
#pragma unroll
  for (int j = 0; j < 2; ++j) {
    int col = n0 + n_off + j * 16 + fr;
    float bv = bias[col];
#pragma unroll
    for (int i = 0; i < 2; ++i) {
#pragma unroll
      for (int r = 0; r < 4; ++r) {
        int row = m0 + m_off + i * 16 + fq * 4 + r;
        Cout[(size_t)row * N + col] = acc[i][j][r] + bv;
      }
    }
  }
}

// ---------------------------------------------------------------------------
// sorted top-4 helpers: total order (value desc, index asc) = jax.lax.top_k
// ---------------------------------------------------------------------------
static __device__ __forceinline__ bool kv_better(float av, int ai, float bv, int bi) {
  return av > bv || (av == bv && ai < bi);
}
static __device__ __forceinline__ void kv_ce(float* v, int* i, int a, int b) {
  if (!kv_better(v[a], i[a], v[b], i[b])) {
    float tv = v[a]; v[a] = v[b]; v[b] = tv;
    int   ti = i[a]; i[a] = i[b]; i[b] = ti;
  }
}
// a,b sorted desc; a <- top-4 of union, sorted desc (bitonic partial merge)
static __device__ __forceinline__ void kv_merge(
    float* av, int* ai, const float* bv, const int* bi) {
  float cv[4]; int ci[4];
#pragma unroll
  for (int j = 0; j < 4; ++j) {
    bool t = kv_better(av[j], ai[j], bv[3 - j], bi[3 - j]);
    cv[j] = t ? av[j] : bv[3 - j];
    ci[j] = t ? ai[j] : bi[3 - j];
  }
  kv_ce(cv, ci, 0, 2); kv_ce(cv, ci, 1, 3);
  kv_ce(cv, ci, 0, 1); kv_ce(cv, ci, 2, 3);
#pragma unroll
  for (int j = 0; j < 4; ++j) { av[j] = cv[j]; ai[j] = ci[j]; }
}

// ---------------------------------------------------------------------------
// transpose+convert body: W[R][Cn] fp32 -> Wt[.][R] bf16, 32x32 tiles
// ---------------------------------------------------------------------------
static __device__ __forceinline__ void transpose_body(
    int t, int nbx, const float* __restrict__ W, unsigned short* __restrict__ Wt,
    int R, int Cn) {
  __shared__ unsigned short tile[32][33];
  const int c0 = (t % nbx) * 32, r0 = (t / nbx) * 32;
  const int tx = threadIdx.x & 31, ty = threadIdx.x >> 5;
#pragma unroll
  for (int i = 0; i < 4; ++i) {
    int r = ty + i * 8;
    tile[r][tx] = f2bf(W[(size_t)(r0 + r) * Cn + c0 + tx]);
  }
  __syncthreads();
#pragma unroll
  for (int i = 0; i < 4; ++i) {
    int r = ty + i * 8;
    Wt[(size_t)(c0 + r) * R + r0 + tx] = tile[tx][r];
  }
}

// ---------------------------------------------------------------------------
// Kernel 1: all input conversions (x->bf16, Wqkv^T, Wproj^T)
// ---------------------------------------------------------------------------
__global__ __launch_bounds__(256) void prep_kernel(
    const float* __restrict__ x, unsigned short* __restrict__ x_bf,
    const float* __restrict__ Wqkv, unsigned short* __restrict__ wqkv_t,
    const float* __restrict__ Wproj, unsigned short* __restrict__ wproj_t) {
  const int bid = blockIdx.x;
  if (bid < 1024) {                       // convert x: 2M elements, 8/thread
    int g = bid * 256 + threadIdx.x;
    const float4* p = (const float4*)x;
    float4 f0 = p[g * 2], f1 = p[g * 2 + 1];
    union { unsigned short u[8]; uint4 v; } pk;
    pk.u[0]=f2bf(f0.x); pk.u[1]=f2bf(f0.y); pk.u[2]=f2bf(f0.z); pk.u[3]=f2bf(f0.w);
    pk.u[4]=f2bf(f1.x); pk.u[5]=f2bf(f1.y); pk.u[6]=f2bf(f1.z); pk.u[7]=f2bf(f1.w);
    ((uint4*)x_bf)[g] = pk.v;
  } else if (bid < 1024 + 768) {          // Wqkv [512,1536] -> [1536,512]
    transpose_body(bid - 1024, C3 / 32, Wqkv, wqkv_t, CC, C3);
  } else {                                // Wproj [512,512] -> ^T
    transpose_body(bid - 1792, CC / 32, Wproj, wproj_t, CC, CC);
  }
}

// ---------------------------------------------------------------------------
// Kernel 2: GEMM1 (qkv, bf16 out), XCD-swizzled, BK=64
// ---------------------------------------------------------------------------
__global__ __launch_bounds__(256) void gemm1_kernel(
    const unsigned short* __restrict__ x_bf,
    const unsigned short* __restrict__ wqkv_t,
    const float* __restrict__ bqkv, unsigned short* __restrict__ qkv_bf) {
  gemm_body<true>(xcd_swz(blockIdx.x, G1_BLOCKS), G1_NT,
                  x_bf, wqkv_t, bqkv, qkv_bf, C3, CC);
}

// ---------------------------------------------------------------------------
// Kernel 3: fused per-row pipeline — ONE tau-row read feeds top-4, the
// logit bias, and the EMA. topk -> sparse attn (4 waves x 2 heads) ->
// signal -> tau EMA+normalize+clip. q loads hoisted before topk so their
// HBM latency hides under the butterfly reduce.
// ---------------------------------------------------------------------------
__global__ __launch_bounds__(256) void row_kernel(
    const unsigned short* __restrict__ qkv, const float* __restrict__ tau,
    unsigned short* __restrict__ attn_bf, float* __restrict__ tau_out) {
  const int row  = blockIdx.x;          // b*T + t
  const int b    = row >> 11;
  const int tid  = threadIdx.x;
  const int wv   = tid >> 6;
  const int lane = tid & 63;

  __shared__ int   idx4[KK];
  __shared__ float tau4[KK];
  __shared__ float ps[HH][KK];
  __shared__ float s3s[KK];
  __shared__ float swv[4][4];
  __shared__ int   swi[4][4];
  __shared__ float wsum[4];
  __shared__ float tot;

  // ---- load tau row once: 8 floats/thread; q loads issued alongside ----
  const float4* rp = (const float4*)(tau + (size_t)row * TT);
  float4 f0 = rp[tid * 2], f1 = rp[tid * 2 + 1];
  float qv[2];
  qv[0] = bf2f(qkv[(size_t)row * C3 + wv * DD + lane]);
  qv[1] = bf2f(qkv[(size_t)row * C3 + (wv + 4) * DD + lane]);
  float e[8] = { f0.x, f0.y, f0.z, f0.w, f1.x, f1.y, f1.z, f1.w };
  const int base = tid * 8;

  // ---- per-thread sorted top-4 of 8 elems ----
  float tv[4] = { -1e30f, -1e30f, -1e30f, -1e30f };
  int   ti[4] = { 1 << 30, 1 << 30, 1 << 30, 1 << 30 };
#pragma unroll
  for (int k = 0; k < 8; ++k) {
    float v = e[k];
    if (v > tv[3]) {                 // strict >: increasing idx keeps earlier
      tv[3] = v; ti[3] = base + k;
      if (tv[3] > tv[2]) { float a=tv[2]; tv[2]=tv[3]; tv[3]=a; int c=ti[2]; ti[2]=ti[3]; ti[3]=c; }
      if (tv[2] > tv[1]) { float a=tv[1]; tv[1]=tv[2]; tv[2]=a; int c=ti[1]; ti[1]=ti[2]; ti[2]=c; }
      if (tv[1] > tv[0]) { float a=tv[0]; tv[0]=tv[1]; tv[1]=a; int c=ti[0]; ti[0]=ti[1]; ti[1]=c; }
    }
  }
  // butterfly allreduce across the wave (6 steps)
#pragma unroll
  for (int step = 1; step <= 32; step <<= 1) {
    float bv[4]; int bi[4];
#pragma unroll
    for (int j = 0; j < 4; ++j) {
      bv[j] = __shfl_xor(tv[j], step, 64);
      bi[j] = __shfl_xor(ti[j], step, 64);
    }
    kv_merge(tv, ti, bv, bi);
  }
  // cross-wave merge via LDS (4 waves)
  if (lane == 0) {
#pragma unroll
    for (int j = 0; j < 4; ++j) { swv[wv][j] = tv[j]; swi[wv][j] = ti[j]; }
  }
  __syncthreads();
  if (tid == 0) {
    float m0[4], m1[4]; int x0[4], x1[4];
#pragma unroll
    for (int j = 0; j < 4; ++j) { m0[j] = swv[0][j]; x0[j] = swi[0][j]; }
#pragma unroll
    for (int j = 0; j < 4; ++j) { m1[j] = swv[1][j]; x1[j] = swi[1][j]; }
    kv_merge(m0, x0, m1, x1);
#pragma unroll
    for (int j = 0; j < 4; ++j) { m1[j] = swv[2][j]; x1[j] = swi[2][j]; }
    float m2[4]; int x2[4];
#pragma unroll
    for (int j = 0; j < 4; ++j) { m2[j] = swv[3][j]; x2[j] = swi[3][j]; }
    kv_merge(m1, x1, m2, x2);
    kv_merge(m0, x0, m1, x1);
#pragma unroll
    for (int j = 0; j < 4; ++j) { idx4[j] = x0[j]; tau4[j] = m0[j]; }
  }
  __syncthreads();

  // ---- sparse attention: wave wv handles heads wv and wv+4 ----
  int   i4[KK]; float t4[KK];
#pragma unroll
  for (int j = 0; j < KK; ++j) { i4[j] = idx4[j]; t4[j] = tau4[j]; }

#pragma unroll
  for (int hh = 0; hh < 2; ++hh) {
    const int h = wv + hh * 4;
    const float q = qv[hh];
    float kv[KK], vv[KK];
#pragma unroll
    for (int j = 0; j < KK; ++j) {
      size_t bs = ((size_t)(b * TT + i4[j])) * C3 + h * DD + lane;
      kv[j] = bf2f(qkv[bs + CC]);
      vv[j] = bf2f(qkv[bs + 2 * CC]);
    }
    float p[KK];
#pragma unroll
    for (int j = 0; j < KK; ++j) p[j] = q * kv[j];
#pragma unroll
    for (int off = 32; off > 0; off >>= 1)
#pragma unroll
      for (int j = 0; j < KK; ++j) p[j] += __shfl_xor(p[j], off, 64);
    float logit[KK];
#pragma unroll
    for (int j = 0; j < KK; ++j)
      logit[j] = p[j] * 0.125f + 2.5f * logf(t4[j] + 1e-8f);
    float m = fmaxf(fmaxf(logit[0], logit[1]), fmaxf(logit[2], logit[3]));
    float den = 0.f;
#pragma unroll
    for (int j = 0; j < KK; ++j) { p[j] = expf(logit[j] - m); den += p[j]; }
    float inv = 1.f / den;
#pragma unroll
    for (int j = 0; j < KK; ++j) p[j] *= inv;
    float o = 0.f;
#pragma unroll
    for (int j = 0; j < KK; ++j) o += p[j] * vv[j];
    attn_bf[(size_t)row * CC + h * DD + lane] = f2bf(o);
    if (lane < KK) ps[h][lane] = p[lane];
  }
  __syncthreads();
  if (tid < KK) {
    float s = 0.f;
#pragma unroll
    for (int k = 0; k < HH; ++k) s += ps[k][tid];
    s *= (1.0f / HH);
    s3s[tid] = s * s * s;
  }
  __syncthreads();

  // ---- tau EMA + normalize + clip on the register-held row ----
  float s3[KK];
#pragma unroll
  for (int j = 0; j < KK; ++j) s3[j] = s3s[j];
  const float keep = 1.0f - 0.085f;
  float local = 0.f;
#pragma unroll
  for (int i = 0; i < 8; ++i) {
    float t = keep * e[i];
#pragma unroll
    for (int j = 0; j < KK; ++j)
      if (base + i == i4[j]) t += s3[j];
    e[i] = t;
    local += t;
  }
#pragma unroll
  for (int off = 32; off > 0; off >>= 1) local += __shfl_xor(local, off, 64);
  if (lane == 0) wsum[wv] = local;
  __syncthreads();
  if (tid == 0) tot = wsum[0] + wsum[1] + wsum[2] + wsum[3];
  __syncthreads();
  float inv = 1.f / (tot + 1e-8f);
  float4* op = (float4*)(tau_out + (size_t)row * TT);
  float4 o0 = { fminf(e[0]*inv,5.f), fminf(e[1]*inv,5.f), fminf(e[2]*inv,5.f), fminf(e[3]*inv,5.f) };
  float4 o1 = { fminf(e[4]*inv,5.f), fminf(e[5]*inv,5.f), fminf(e[6]*inv,5.f), fminf(e[7]*inv,5.f) };
  op[tid * 2] = o0;
  op[tid * 2 + 1] = o1;
}

// ---------------------------------------------------------------------------
// Kernel 4: GEMM2 (out, fp32), 64x64 tiles, BK=64, XCD-swizzled
// ---------------------------------------------------------------------------
__global__ __launch_bounds__(256) void gemm2_kernel(
    const unsigned short* __restrict__ attn_bf,
    const unsigned short* __restrict__ wproj_t,
    const float* __restrict__ bproj, float* __restrict__ out) {
  gemm_body64(xcd_swz(blockIdx.x, G2_BLOCKS), G2_NT,
              attn_bf, wproj_t, bproj, out, CC, CC);
}

// ---------------------------------------------------------------------------
extern "C" void kernel_launch(void* const* d_in, const int* in_sizes, int n_in,
                              void* d_out, int out_size, void* d_ws, size_t ws_size,
                              hipStream_t stream) {
  const float* x     = (const float*)d_in[0];   // [B,T,C]
  const float* tau   = (const float*)d_in[1];   // [B,T,T]
  const float* Wqkv  = (const float*)d_in[2];   // [C,3C]
  const float* bqkv  = (const float*)d_in[3];   // [3C]
  const float* Wproj = (const float*)d_in[4];   // [C,C]
  const float* bproj = (const float*)d_in[5];   // [C]

  float* out     = (float*)d_out;               // [B,T,C]
  float* tau_new = out + (size_t)MROWS * CC;    // [B,T,T]

  char* w = (char*)d_ws;
  unsigned short* qkv_bf  = (unsigned short*)w; w += (size_t)MROWS * C3 * 2;
  unsigned short* x_bf    = (unsigned short*)w; w += (size_t)MROWS * CC * 2;
  unsigned short* wqkv_t  = (unsigned short*)w; w += (size_t)C3 * CC * 2;
  unsigned short* wproj_t = (unsigned short*)w; w += (size_t)CC * CC * 2;
  unsigned short* attn_bf = (unsigned short*)w;

  // 1) converts: x->bf16, Wqkv^T, Wproj^T
  prep_kernel<<<2048, 256, 0, stream>>>(x, x_bf, Wqkv, wqkv_t, Wproj, wproj_t);

  // 2) qkv GEMM (bf16 out), XCD-swizzled, BK=64
  gemm1_kernel<<<G1_BLOCKS, 256, 0, stream>>>(x_bf, wqkv_t, bqkv, qkv_bf);

  // 3) fused per-row: topk + sparse attn + tau EMA (tau row read ONCE)
  row_kernel<<<MROWS, 256, 0, stream>>>(qkv_bf, tau, attn_bf, tau_new);

  // 4) out GEMM (fp32), 64x64 tiles, BK=64, XCD-swizzled
  gemm2_kernel<<<G2_BLOCKS, 256, 0, stream>>>(attn_bf, wproj_t, bproj, out);
}